// Round 12
// baseline (60.633 us; speedup 1.0000x reference)
//
#include <hip/hip_runtime.h>
#include <math.h>

#define N_NODES 10000
#define N_EDGES 320000
#define D 256
#define HALF (N_NODES / 2)
#define CAP_H 64  // per-node per-src-half cap; deg_half ~ Poisson(16), P(>64) ~ 1e-19
#define BM 48     // GEMM row-tile: ceil(10000/48)=209 blocks <= 256 CUs (balanced)
#define LDK 40    // LDS k-stride in ushorts (80 B rows: 16B-aligned, bank-spread)
#define GB_GEMM ((N_NODES + BM - 1) / BM)      // 209
#define GB_BUILD ((N_EDGES + 511) / 512)       // 625 (2 edges/thread)

typedef __attribute__((ext_vector_type(8))) short short8;
typedef __attribute__((ext_vector_type(4))) float f32x4;

__device__ __forceinline__ ushort f2bf(float f) {
    union { float f; unsigned u; } v; v.f = f;
    unsigned r = v.u + 0x7FFFu + ((v.u >> 16) & 1u);  // RNE
    return (ushort)(r >> 16);
}
__device__ __forceinline__ float bf2f(ushort u) {
    union { unsigned u; float f; } v; v.u = (unsigned)u << 16;
    return v.f;
}
__device__ __forceinline__ short8 cvt8(const float4 a, const float4 b) {
    short8 r;
    r[0] = f2bf(a.x); r[1] = f2bf(a.y); r[2] = f2bf(a.z); r[3] = f2bf(a.w);
    r[4] = f2bf(b.x); r[5] = f2bf(b.y); r[6] = f2bf(b.z); r[7] = f2bf(b.w);
    return r;
}

// ---------------- K1: W fp32 -> bf16 (once) + zero deg (both halves) ----------------
__global__ __launch_bounds__(256) void k_prep(const float* __restrict__ W,
                                              ushort* __restrict__ Wb,
                                              unsigned* __restrict__ deg) {
    const int tid = blockIdx.x * 256 + threadIdx.x;
    const int i = tid * 4;
    const float4 v = *(const float4*)&W[i];
    ushort4 o;
    o.x = f2bf(v.x); o.y = f2bf(v.y); o.z = f2bf(v.z); o.w = f2bf(v.w);
    *(ushort4*)&Wb[i] = o;
    for (int j = tid; j < 2 * N_NODES; j += (D * D) / 4) deg[j] = 0u;
}

// ---------------- K2 (fat): GEMM-fused (BM=48) + edge scatter (split CSR) ----------------
// GEMM: 48 rows x 256 cols per block; 4 waves, wave w owns col strip [w*64,+64).
// Double-buffered LDS, 1 barrier/K-iter. Epilogue: row norm + sigmoid magnitude
// -> hb (bf16), es = exp(h.a_s). Scatter: 2 edges/thread, src-half-split CSR.
__global__ __launch_bounds__(256) void k_main(const float* __restrict__ x,
                                              const ushort* __restrict__ Wb,
                                              const float* __restrict__ b,
                                              const float* __restrict__ mag_w,
                                              const float* __restrict__ mag_b,
                                              const float* __restrict__ attn_w,
                                              const int* __restrict__ ei,
                                              unsigned* __restrict__ deg,
                                              int* __restrict__ csr,
                                              ushort* __restrict__ hb,
                                              float* __restrict__ es) {
    if (blockIdx.x >= GB_GEMM) {
        const int base = (blockIdx.x - GB_GEMM) * 512 + threadIdx.x;
#pragma unroll
        for (int k = 0; k < 2; ++k) {
            const int e = base + k * 256;
            if (e < N_EDGES) {
                int src = ei[e];
                int tgt = ei[N_EDGES + e];
                src = min(max(src, 0), N_NODES - 1);
                tgt = min(max(tgt, 0), N_NODES - 1);
                const int half = (src >= HALF);
                const unsigned slot = atomicAdd(&deg[tgt + half * N_NODES], 1u);
                if (slot < CAP_H)
                    csr[((size_t)tgt * 2 + half) * CAP_H + slot] = src;
            }
        }
        return;
    }

    __shared__ ushort ldsA[2][BM * LDK];
    __shared__ ushort ldsB[2][256 * LDK];
    __shared__ float red_ssq[4][BM], red_ra[4][BM];
    __shared__ float smrow[BM], scl[BM];

    const int t = threadIdx.x;
    const int w = t >> 6, l = t & 63;
    const int bm = blockIdx.x * BM;
    // A staging: 4 thr/row x 8 floats; rows 0..63 mapped, only sra<48 active
    const int sra = t >> 2, ka = (t & 3) * 8;
    const bool arow = (sra < BM);
    const int am = bm + sra;
    // B staging: 4 thr/row x 8 bf16, 4 row-groups of 64
    const int srb = t >> 2, kb = (t & 3) * 8;
    const int fl = l & 15;
    const int fh = (l >> 4) * 8;
    const int rq = (l >> 4) * 4;

    f32x4 acc[3][4];
#pragma unroll
    for (int r = 0; r < 3; ++r)
#pragma unroll
        for (int c = 0; c < 4; ++c) acc[r][c] = (f32x4)(0.f);
    float sm_part = 0.f;

    float4 xa0, xa1;
    short8 bv[4];

    // prologue: stage k0 = 0
    {
        xa0 = make_float4(0.f, 0.f, 0.f, 0.f); xa1 = xa0;
        if (arow && am < N_NODES) {
            xa0 = *(const float4*)&x[(size_t)am * D + ka];
            xa1 = *(const float4*)&x[(size_t)am * D + ka + 4];
        }
        const float4 mw0 = *(const float4*)&mag_w[ka];
        const float4 mw1 = *(const float4*)&mag_w[ka + 4];
        sm_part += xa0.x * mw0.x + xa0.y * mw0.y + xa0.z * mw0.z + xa0.w * mw0.w
                 + xa1.x * mw1.x + xa1.y * mw1.y + xa1.z * mw1.z + xa1.w * mw1.w;
#pragma unroll
        for (int p = 0; p < 4; ++p)
            bv[p] = *(const short8*)&Wb[(size_t)(p * 64 + srb) * D + kb];
        if (arow) *(short8*)&ldsA[0][sra * LDK + ka] = cvt8(xa0, xa1);
#pragma unroll
        for (int p = 0; p < 4; ++p)
            *(short8*)&ldsB[0][(p * 64 + srb) * LDK + kb] = bv[p];
    }
    __syncthreads();

    int cur = 0;
    for (int k0 = 32; k0 < D; k0 += 32) {
        // issue next tile's global loads (hide under MFMA below)
        xa0 = make_float4(0.f, 0.f, 0.f, 0.f); xa1 = xa0;
        if (arow && am < N_NODES) {
            xa0 = *(const float4*)&x[(size_t)am * D + k0 + ka];
            xa1 = *(const float4*)&x[(size_t)am * D + k0 + ka + 4];
        }
        const float4 mw0 = *(const float4*)&mag_w[k0 + ka];
        const float4 mw1 = *(const float4*)&mag_w[k0 + ka + 4];
        sm_part += xa0.x * mw0.x + xa0.y * mw0.y + xa0.z * mw0.z + xa0.w * mw0.w
                 + xa1.x * mw1.x + xa1.y * mw1.y + xa1.z * mw1.z + xa1.w * mw1.w;
#pragma unroll
        for (int p = 0; p < 4; ++p)
            bv[p] = *(const short8*)&Wb[(size_t)(p * 64 + srb) * D + k0 + kb];

        // compute on current buffer
        short8 af[3], bfr[4];
#pragma unroll
        for (int r = 0; r < 3; ++r)
            af[r] = *(short8*)&ldsA[cur][(r * 16 + fl) * LDK + fh];
#pragma unroll
        for (int c = 0; c < 4; ++c)
            bfr[c] = *(short8*)&ldsB[cur][(w * 64 + c * 16 + fl) * LDK + fh];
#pragma unroll
        for (int r = 0; r < 3; ++r)
#pragma unroll
            for (int c = 0; c < 4; ++c)
                acc[r][c] = __builtin_amdgcn_mfma_f32_16x16x32_bf16(af[r], bfr[c], acc[r][c], 0, 0, 0);

        // write next buffer, single barrier
        if (arow) *(short8*)&ldsA[cur ^ 1][sra * LDK + ka] = cvt8(xa0, xa1);
#pragma unroll
        for (int p = 0; p < 4; ++p)
            *(short8*)&ldsB[cur ^ 1][(p * 64 + srb) * LDK + kb] = bv[p];
        __syncthreads();
        cur ^= 1;
    }
    // last tile compute
    {
        short8 af[3], bfr[4];
#pragma unroll
        for (int r = 0; r < 3; ++r)
            af[r] = *(short8*)&ldsA[cur][(r * 16 + fl) * LDK + fh];
#pragma unroll
        for (int c = 0; c < 4; ++c)
            bfr[c] = *(short8*)&ldsB[cur][(w * 64 + c * 16 + fl) * LDK + fh];
#pragma unroll
        for (int r = 0; r < 3; ++r)
#pragma unroll
            for (int c = 0; c < 4; ++c)
                acc[r][c] = __builtin_amdgcn_mfma_f32_16x16x32_bf16(af[r], bfr[c], acc[r][c], 0, 0, 0);
    }

    // mag dot: reduce across the 4 staging threads of each row (consecutive lanes)
#pragma unroll
    for (int o = 1; o < 4; o <<= 1) sm_part += __shfl_xor(sm_part, o);
    if ((t & 3) == 0 && arow) smrow[sra] = sm_part;

    float bn[4], asn[4];
#pragma unroll
    for (int c = 0; c < 4; ++c) {
        const int n = w * 64 + c * 16 + fl;
        bn[c]  = b[n];
        asn[c] = attn_w[n];
    }

    // row reductions (ssq, h.a_s) within wave, then LDS cross-wave
#pragma unroll
    for (int r = 0; r < 3; ++r) {
#pragma unroll
        for (int reg = 0; reg < 4; ++reg) {
            float vssq = 0.f, vra = 0.f;
#pragma unroll
            for (int c = 0; c < 4; ++c) {
                const float v = acc[r][c][reg] + bn[c];
                vssq += v * v;
                vra  += v * asn[c];
            }
#pragma unroll
            for (int o = 1; o < 16; o <<= 1) {
                vssq += __shfl_xor(vssq, o);
                vra  += __shfl_xor(vra, o);
            }
            if (fl == 0) {
                const int m = r * 16 + rq + reg;
                red_ssq[w][m] = vssq;
                red_ra[w][m]  = vra;
            }
        }
    }
    __syncthreads();

    if (t < BM) {
        const int gm = bm + t;
        const float ssq = red_ssq[0][t] + red_ssq[1][t] + red_ssq[2][t] + red_ssq[3][t];
        const float ra  = red_ra[0][t]  + red_ra[1][t]  + red_ra[2][t]  + red_ra[3][t];
        const float norm = sqrtf(ssq);
        const float mag  = 1.5f / (1.f + expf(-(smrow[t] + mag_b[0])));
        const float scale = mag / fmaxf(norm, 1e-12f);
        scl[t] = scale;
        if (gm < N_NODES) es[gm] = expf(ra * scale);   // exp(s_s); |s_s| <= ~1.1
    }
    __syncthreads();

    // write hb = bf16(h_raw * scale)
#pragma unroll
    for (int r = 0; r < 3; ++r) {
#pragma unroll
        for (int reg = 0; reg < 4; ++reg) {
            const int ml = r * 16 + rq + reg;
            const int m = bm + ml;
            if (m < N_NODES) {
                const float scale = scl[ml];
#pragma unroll
                for (int c = 0; c < 4; ++c) {
                    const int n = w * 64 + c * 16 + fl;
                    hb[(size_t)m * D + n] = f2bf((acc[r][c][reg] + bn[c]) * scale);
                }
            }
        }
    }
}

// ---------------- K3: two-pass (src-half) gather + expmap0 + clip ----------------
// 1 wave per node, 8 nodes/block (512 thr). attn = es[src]/Σes[src] (s_t cancels
// in segment softmax; |s_s|<=1.1 so no max-shift). Half-list <= 64 = one lane reg.
__global__ __launch_bounds__(512) void k_agg(const ushort* __restrict__ hb,
                                             const unsigned* __restrict__ deg,
                                             const int* __restrict__ csr,
                                             const float* __restrict__ es,
                                             float* __restrict__ out) {
    const int wv = threadIdx.x >> 6;
    const int n = blockIdx.x * 8 + wv;
    const int lane = threadIdx.x & 63;
    const int d0 = min((int)deg[n], CAP_H);
    const int d1 = min((int)deg[n + N_NODES], CAP_H);
    const size_t cbase = (size_t)n * 2 * CAP_H;

    int src0 = 0, src1 = 0;
    float w0 = 0.f, w1 = 0.f;
    if (lane < d0) { src0 = csr[cbase + lane];         w0 = es[src0]; }
    if (lane < d1) { src1 = csr[cbase + CAP_H + lane]; w1 = es[src1]; }
    float sum = w0 + w1;
#pragma unroll
    for (int o = 32; o > 0; o >>= 1) sum += __shfl_xor(sum, o);
    const float inv = 1.f / (sum + 1e-10f);

    const int coff = lane * 4;
    float4 A0 = make_float4(0.f, 0.f, 0.f, 0.f), A1 = A0, A2 = A0, A3 = A0;

#pragma unroll
    for (int pass = 0; pass < 2; ++pass) {
        const int cnt = pass ? d1 : d0;
        const int sreg = pass ? src1 : src0;
        const float wreg = pass ? w1 : w0;
        int e = 0;
        for (; e + 8 <= cnt; e += 8) {
            int s[8]; float q[8]; ushort4 v[8];
#pragma unroll
            for (int j = 0; j < 8; ++j) { s[j] = __shfl(sreg, e + j); q[j] = __shfl(wreg, e + j); }
#pragma unroll
            for (int j = 0; j < 8; ++j) v[j] = *(const ushort4*)&hb[(size_t)s[j] * D + coff];
#pragma unroll
            for (int j = 0; j < 8; ++j) {
                float4* A = (j & 2) ? ((j & 1) ? &A3 : &A2) : ((j & 1) ? &A1 : &A0);
                A->x += q[j] * bf2f(v[j].x); A->y += q[j] * bf2f(v[j].y);
                A->z += q[j] * bf2f(v[j].z); A->w += q[j] * bf2f(v[j].w);
            }
        }
        for (; e < cnt; ++e) {
            const int s0 = __shfl(sreg, e);
            const float q0 = __shfl(wreg, e);
            const ushort4 v0 = *(const ushort4*)&hb[(size_t)s0 * D + coff];
            A0.x += q0 * bf2f(v0.x); A0.y += q0 * bf2f(v0.y); A0.z += q0 * bf2f(v0.z); A0.w += q0 * bf2f(v0.w);
        }
    }
    float4 acc = make_float4((A0.x + A1.x + A2.x + A3.x) * inv,
                             (A0.y + A1.y + A2.y + A3.y) * inv,
                             (A0.z + A1.z + A2.z + A3.z) * inv,
                             (A0.w + A1.w + A2.w + A3.w) * inv);

    const ushort4 hnv = *(const ushort4*)&hb[(size_t)n * D + coff];
    float4 u = make_float4(bf2f(hnv.x) + acc.x, bf2f(hnv.y) + acc.y,
                           bf2f(hnv.z) + acc.z, bf2f(hnv.w) + acc.w);
    float ssq = u.x * u.x + u.y * u.y + u.z * u.z + u.w * u.w;
#pragma unroll
    for (int o = 32; o > 0; o >>= 1) ssq += __shfl_xor(ssq, o);
    const float un = sqrtf(ssq);
    const float un_c = fmaxf(un, 1e-15f);
    const float th = tanhf(un_c);
    float s = th / un_c;
    const float pn = th * (un / un_c);
    if (pn > 0.95f) s *= 0.95f / (pn + 1e-8f);
    float4 p = make_float4(u.x * s, u.y * s, u.z * s, u.w * s);
    *(float4*)&out[(size_t)n * D + coff] = p;
}

// ---------------- launch ----------------
extern "C" void kernel_launch(void* const* d_in, const int* in_sizes, int n_in,
                              void* d_out, int out_size, void* d_ws, size_t ws_size,
                              hipStream_t stream) {
    const float* x      = (const float*)d_in[0];
    const int*   ei     = (const int*)d_in[1];
    const float* W      = (const float*)d_in[2];
    const float* b      = (const float*)d_in[3];
    const float* mag_w  = (const float*)d_in[4];
    const float* mag_b  = (const float*)d_in[5];
    const float* attn_w = (const float*)d_in[6];
    float* out = (float*)d_out;

    char* ws = (char*)d_ws;
    ushort* hb = (ushort*)ws;         ws += (size_t)N_NODES * D * sizeof(ushort);
    float* es = (float*)ws;           ws += (size_t)N_NODES * sizeof(float);
    unsigned* deg = (unsigned*)ws;    ws += (size_t)2 * N_NODES * sizeof(unsigned);
    int* csr = (int*)ws;              ws += (size_t)N_NODES * 2 * CAP_H * sizeof(int);
    ushort* Wb = (ushort*)ws;         ws += (size_t)D * D * sizeof(ushort);

    k_prep<<<(D * D) / (256 * 4), 256, 0, stream>>>(W, Wb, deg);
    k_main<<<GB_GEMM + GB_BUILD, 256, 0, stream>>>(
        x, Wb, b, mag_w, mag_b, attn_w, ei, deg, csr, hb, es);
    k_agg<<<N_NODES / 8, 512, 0, stream>>>(hb, deg, csr, es, out);
}

// Round 13
// 54.881 us; speedup vs baseline: 1.1048x; 1.1048x over previous
//
#include <hip/hip_runtime.h>
#include <math.h>

#define N_NODES 10000
#define N_EDGES 320000
#define D 256
#define HALF (N_NODES / 2)
#define CAP_H 64  // per-node per-src-half cap; deg_half ~ Poisson(16), P(>64) ~ 1e-19
#define BM 48     // GEMM row-tile: ceil(10000/48)=209 blocks <= 256 CUs (balanced)
#define LDK 40    // LDS k-stride in ushorts (80 B rows: 16B-aligned, bank-spread)
#define GB_GEMM ((N_NODES + BM - 1) / BM)      // 209
#define GB_BUILD ((N_EDGES + 255) / 256)       // 1250

typedef __attribute__((ext_vector_type(8))) short short8;
typedef __attribute__((ext_vector_type(4))) float f32x4;

__device__ __forceinline__ ushort f2bf(float f) {
    union { float f; unsigned u; } v; v.f = f;
    unsigned r = v.u + 0x7FFFu + ((v.u >> 16) & 1u);  // RNE
    return (ushort)(r >> 16);
}
__device__ __forceinline__ float bf2f(ushort u) {
    union { unsigned u; float f; } v; v.u = (unsigned)u << 16;
    return v.f;
}
__device__ __forceinline__ short8 cvt8(const float4 a, const float4 b) {
    short8 r;
    r[0] = f2bf(a.x); r[1] = f2bf(a.y); r[2] = f2bf(a.z); r[3] = f2bf(a.w);
    r[4] = f2bf(b.x); r[5] = f2bf(b.y); r[6] = f2bf(b.z); r[7] = f2bf(b.w);
    return r;
}

// ---------------- K1: W fp32 -> bf16 (once) + zero deg (both halves) ----------------
__global__ __launch_bounds__(256) void k_prep(const float* __restrict__ W,
                                              ushort* __restrict__ Wb,
                                              unsigned* __restrict__ deg) {
    const int tid = blockIdx.x * 256 + threadIdx.x;
    const int i = tid * 4;
    const float4 v = *(const float4*)&W[i];
    ushort4 o;
    o.x = f2bf(v.x); o.y = f2bf(v.y); o.z = f2bf(v.z); o.w = f2bf(v.w);
    *(ushort4*)&Wb[i] = o;
    for (int j = tid; j < 2 * N_NODES; j += (D * D) / 4) deg[j] = 0u;
}

// ---------------- K2 (fat): GEMM-fused (BM=48) + edge scatter (split CSR) ----------------
// GEMM: 48 rows x 256 cols per block; 4 waves, wave w owns col strip [w*64,+64).
// Double-buffered LDS. Epilogue: row norm + sigmoid magnitude -> hb, es = exp(h.a_s).
// Scatter: CSR split by src half (agg per-pass working set 2.56 MB, L2-friendly).
__global__ __launch_bounds__(256) void k_main(const float* __restrict__ x,
                                              const ushort* __restrict__ Wb,
                                              const float* __restrict__ b,
                                              const float* __restrict__ mag_w,
                                              const float* __restrict__ mag_b,
                                              const float* __restrict__ attn_w,
                                              const int* __restrict__ ei,
                                              unsigned* __restrict__ deg,
                                              int* __restrict__ csr,
                                              ushort* __restrict__ hb,
                                              float* __restrict__ es) {
    if (blockIdx.x >= GB_GEMM) {
        const int e = (blockIdx.x - GB_GEMM) * 256 + threadIdx.x;
        if (e < N_EDGES) {
            int src = ei[e];
            int tgt = ei[N_EDGES + e];
            src = min(max(src, 0), N_NODES - 1);
            tgt = min(max(tgt, 0), N_NODES - 1);
            const int half = (src >= HALF);
            const unsigned slot = atomicAdd(&deg[tgt + half * N_NODES], 1u);
            if (slot < CAP_H)
                csr[((size_t)tgt * 2 + half) * CAP_H + slot] = src;
        }
        return;
    }

    __shared__ ushort ldsA[2][BM * LDK];
    __shared__ ushort ldsB[2][256 * LDK];
    __shared__ float red_ssq[4][BM], red_ra[4][BM];
    __shared__ float smrow[BM], scl[BM];

    const int t = threadIdx.x;
    const int w = t >> 6, l = t & 63;
    const int bm = blockIdx.x * BM;
    // A staging: 4 thr/row x 8 floats; rows 0..63 mapped, only sra<48 active
    const int sra = t >> 2, ka = (t & 3) * 8;
    const bool arow = (sra < BM);
    const int am = bm + sra;
    // B staging: 4 thr/row x 8 bf16, 4 row-groups of 64
    const int srb = t >> 2, kb = (t & 3) * 8;
    const int fl = l & 15;
    const int fh = (l >> 4) * 8;
    const int rq = (l >> 4) * 4;

    f32x4 acc[3][4];
#pragma unroll
    for (int r = 0; r < 3; ++r)
#pragma unroll
        for (int c = 0; c < 4; ++c) acc[r][c] = (f32x4)(0.f);
    float sm_part = 0.f;

    float4 xa0, xa1;
    short8 bv[4];

    // prologue: stage k0 = 0
    {
        xa0 = make_float4(0.f, 0.f, 0.f, 0.f); xa1 = xa0;
        if (arow && am < N_NODES) {
            xa0 = *(const float4*)&x[(size_t)am * D + ka];
            xa1 = *(const float4*)&x[(size_t)am * D + ka + 4];
        }
        const float4 mw0 = *(const float4*)&mag_w[ka];
        const float4 mw1 = *(const float4*)&mag_w[ka + 4];
        sm_part += xa0.x * mw0.x + xa0.y * mw0.y + xa0.z * mw0.z + xa0.w * mw0.w
                 + xa1.x * mw1.x + xa1.y * mw1.y + xa1.z * mw1.z + xa1.w * mw1.w;
#pragma unroll
        for (int p = 0; p < 4; ++p)
            bv[p] = *(const short8*)&Wb[(size_t)(p * 64 + srb) * D + kb];
        if (arow) *(short8*)&ldsA[0][sra * LDK + ka] = cvt8(xa0, xa1);
#pragma unroll
        for (int p = 0; p < 4; ++p)
            *(short8*)&ldsB[0][(p * 64 + srb) * LDK + kb] = bv[p];
    }
    __syncthreads();

    int cur = 0;
    for (int k0 = 32; k0 < D; k0 += 32) {
        // issue next tile's global loads (hide under MFMA below)
        xa0 = make_float4(0.f, 0.f, 0.f, 0.f); xa1 = xa0;
        if (arow && am < N_NODES) {
            xa0 = *(const float4*)&x[(size_t)am * D + k0 + ka];
            xa1 = *(const float4*)&x[(size_t)am * D + k0 + ka + 4];
        }
        const float4 mw0 = *(const float4*)&mag_w[k0 + ka];
        const float4 mw1 = *(const float4*)&mag_w[k0 + ka + 4];
        sm_part += xa0.x * mw0.x + xa0.y * mw0.y + xa0.z * mw0.z + xa0.w * mw0.w
                 + xa1.x * mw1.x + xa1.y * mw1.y + xa1.z * mw1.z + xa1.w * mw1.w;
#pragma unroll
        for (int p = 0; p < 4; ++p)
            bv[p] = *(const short8*)&Wb[(size_t)(p * 64 + srb) * D + k0 + kb];

        // compute on current buffer
        short8 af[3], bfr[4];
#pragma unroll
        for (int r = 0; r < 3; ++r)
            af[r] = *(short8*)&ldsA[cur][(r * 16 + fl) * LDK + fh];
#pragma unroll
        for (int c = 0; c < 4; ++c)
            bfr[c] = *(short8*)&ldsB[cur][(w * 64 + c * 16 + fl) * LDK + fh];
#pragma unroll
        for (int r = 0; r < 3; ++r)
#pragma unroll
            for (int c = 0; c < 4; ++c)
                acc[r][c] = __builtin_amdgcn_mfma_f32_16x16x32_bf16(af[r], bfr[c], acc[r][c], 0, 0, 0);

        // write next buffer, single barrier
        if (arow) *(short8*)&ldsA[cur ^ 1][sra * LDK + ka] = cvt8(xa0, xa1);
#pragma unroll
        for (int p = 0; p < 4; ++p)
            *(short8*)&ldsB[cur ^ 1][(p * 64 + srb) * LDK + kb] = bv[p];
        __syncthreads();
        cur ^= 1;
    }
    // last tile compute
    {
        short8 af[3], bfr[4];
#pragma unroll
        for (int r = 0; r < 3; ++r)
            af[r] = *(short8*)&ldsA[cur][(r * 16 + fl) * LDK + fh];
#pragma unroll
        for (int c = 0; c < 4; ++c)
            bfr[c] = *(short8*)&ldsB[cur][(w * 64 + c * 16 + fl) * LDK + fh];
#pragma unroll
        for (int r = 0; r < 3; ++r)
#pragma unroll
            for (int c = 0; c < 4; ++c)
                acc[r][c] = __builtin_amdgcn_mfma_f32_16x16x32_bf16(af[r], bfr[c], acc[r][c], 0, 0, 0);
    }

    // mag dot: reduce across the 4 staging threads of each row (consecutive lanes)
#pragma unroll
    for (int o = 1; o < 4; o <<= 1) sm_part += __shfl_xor(sm_part, o);
    if ((t & 3) == 0 && arow) smrow[sra] = sm_part;

    float bn[4], asn[4];
#pragma unroll
    for (int c = 0; c < 4; ++c) {
        const int n = w * 64 + c * 16 + fl;
        bn[c]  = b[n];
        asn[c] = attn_w[n];
    }

    // row reductions (ssq, h.a_s) within wave, then LDS cross-wave
#pragma unroll
    for (int r = 0; r < 3; ++r) {
#pragma unroll
        for (int reg = 0; reg < 4; ++reg) {
            float vssq = 0.f, vra = 0.f;
#pragma unroll
            for (int c = 0; c < 4; ++c) {
                const float v = acc[r][c][reg] + bn[c];
                vssq += v * v;
                vra  += v * asn[c];
            }
#pragma unroll
            for (int o = 1; o < 16; o <<= 1) {
                vssq += __shfl_xor(vssq, o);
                vra  += __shfl_xor(vra, o);
            }
            if (fl == 0) {
                const int m = r * 16 + rq + reg;
                red_ssq[w][m] = vssq;
                red_ra[w][m]  = vra;
            }
        }
    }
    __syncthreads();

    if (t < BM) {
        const int gm = bm + t;
        const float ssq = red_ssq[0][t] + red_ssq[1][t] + red_ssq[2][t] + red_ssq[3][t];
        const float ra  = red_ra[0][t]  + red_ra[1][t]  + red_ra[2][t]  + red_ra[3][t];
        const float norm = sqrtf(ssq);
        const float mag  = 1.5f / (1.f + expf(-(smrow[t] + mag_b[0])));
        const float scale = mag / fmaxf(norm, 1e-12f);
        scl[t] = scale;
        if (gm < N_NODES) es[gm] = expf(ra * scale);   // exp(s_s); |s_s| <= ~1.1
    }
    __syncthreads();

    // write hb = bf16(h_raw * scale)
#pragma unroll
    for (int r = 0; r < 3; ++r) {
#pragma unroll
        for (int reg = 0; reg < 4; ++reg) {
            const int ml = r * 16 + rq + reg;
            const int m = bm + ml;
            if (m < N_NODES) {
                const float scale = scl[ml];
#pragma unroll
                for (int c = 0; c < 4; ++c) {
                    const int n = w * 64 + c * 16 + fl;
                    hb[(size_t)m * D + n] = f2bf((acc[r][c][reg] + bn[c]) * scale);
                }
            }
        }
    }
}

// ---------------- K3: two-pass (src-half) gather + expmap0 + clip ----------------
// 1 wave per node, 4 nodes/block. attn = es[src]/Σes[src] (s_t cancels in segment
// softmax; |s_s|<=1.1 so no max-shift). Each half-list <= 64 = one lane register.
__global__ __launch_bounds__(256) void k_agg(const ushort* __restrict__ hb,
                                             const unsigned* __restrict__ deg,
                                             const int* __restrict__ csr,
                                             const float* __restrict__ es,
                                             float* __restrict__ out) {
    const int wv = threadIdx.x >> 6;
    const int n = blockIdx.x * 4 + wv;
    const int lane = threadIdx.x & 63;
    const int d0 = min((int)deg[n], CAP_H);
    const int d1 = min((int)deg[n + N_NODES], CAP_H);
    const size_t cbase = (size_t)n * 2 * CAP_H;

    int src0 = 0, src1 = 0;
    float w0 = 0.f, w1 = 0.f;
    if (lane < d0) { src0 = csr[cbase + lane];         w0 = es[src0]; }
    if (lane < d1) { src1 = csr[cbase + CAP_H + lane]; w1 = es[src1]; }
    float sum = w0 + w1;
#pragma unroll
    for (int o = 32; o > 0; o >>= 1) sum += __shfl_xor(sum, o);
    const float inv = 1.f / (sum + 1e-10f);

    const int coff = lane * 4;
    float4 A0 = make_float4(0.f, 0.f, 0.f, 0.f), A1 = A0, A2 = A0, A3 = A0;

#pragma unroll
    for (int pass = 0; pass < 2; ++pass) {
        const int cnt = pass ? d1 : d0;
        const int sreg = pass ? src1 : src0;
        const float wreg = pass ? w1 : w0;
        int e = 0;
        for (; e + 8 <= cnt; e += 8) {
            int s[8]; float q[8]; ushort4 v[8];
#pragma unroll
            for (int j = 0; j < 8; ++j) { s[j] = __shfl(sreg, e + j); q[j] = __shfl(wreg, e + j); }
#pragma unroll
            for (int j = 0; j < 8; ++j) v[j] = *(const ushort4*)&hb[(size_t)s[j] * D + coff];
#pragma unroll
            for (int j = 0; j < 8; ++j) {
                float4* A = (j & 2) ? ((j & 1) ? &A3 : &A2) : ((j & 1) ? &A1 : &A0);
                A->x += q[j] * bf2f(v[j].x); A->y += q[j] * bf2f(v[j].y);
                A->z += q[j] * bf2f(v[j].z); A->w += q[j] * bf2f(v[j].w);
            }
        }
        for (; e < cnt; ++e) {
            const int s0 = __shfl(sreg, e);
            const float q0 = __shfl(wreg, e);
            const ushort4 v0 = *(const ushort4*)&hb[(size_t)s0 * D + coff];
            A0.x += q0 * bf2f(v0.x); A0.y += q0 * bf2f(v0.y); A0.z += q0 * bf2f(v0.z); A0.w += q0 * bf2f(v0.w);
        }
    }
    float4 acc = make_float4((A0.x + A1.x + A2.x + A3.x) * inv,
                             (A0.y + A1.y + A2.y + A3.y) * inv,
                             (A0.z + A1.z + A2.z + A3.z) * inv,
                             (A0.w + A1.w + A2.w + A3.w) * inv);

    const ushort4 hnv = *(const ushort4*)&hb[(size_t)n * D + coff];
    float4 u = make_float4(bf2f(hnv.x) + acc.x, bf2f(hnv.y) + acc.y,
                           bf2f(hnv.z) + acc.z, bf2f(hnv.w) + acc.w);
    float ssq = u.x * u.x + u.y * u.y + u.z * u.z + u.w * u.w;
#pragma unroll
    for (int o = 32; o > 0; o >>= 1) ssq += __shfl_xor(ssq, o);
    const float un = sqrtf(ssq);
    const float un_c = fmaxf(un, 1e-15f);
    const float th = tanhf(un_c);
    float s = th / un_c;
    const float pn = th * (un / un_c);
    if (pn > 0.95f) s *= 0.95f / (pn + 1e-8f);
    float4 p = make_float4(u.x * s, u.y * s, u.z * s, u.w * s);
    *(float4*)&out[(size_t)n * D + coff] = p;
}

// ---------------- launch ----------------
extern "C" void kernel_launch(void* const* d_in, const int* in_sizes, int n_in,
                              void* d_out, int out_size, void* d_ws, size_t ws_size,
                              hipStream_t stream) {
    const float* x      = (const float*)d_in[0];
    const int*   ei     = (const int*)d_in[1];
    const float* W      = (const float*)d_in[2];
    const float* b      = (const float*)d_in[3];
    const float* mag_w  = (const float*)d_in[4];
    const float* mag_b  = (const float*)d_in[5];
    const float* attn_w = (const float*)d_in[6];
    float* out = (float*)d_out;

    char* ws = (char*)d_ws;
    ushort* hb = (ushort*)ws;         ws += (size_t)N_NODES * D * sizeof(ushort);
    float* es = (float*)ws;           ws += (size_t)N_NODES * sizeof(float);
    unsigned* deg = (unsigned*)ws;    ws += (size_t)2 * N_NODES * sizeof(unsigned);
    int* csr = (int*)ws;              ws += (size_t)N_NODES * 2 * CAP_H * sizeof(int);
    ushort* Wb = (ushort*)ws;         ws += (size_t)D * D * sizeof(ushort);

    k_prep<<<(D * D) / (256 * 4), 256, 0, stream>>>(W, Wb, deg);
    k_main<<<GB_GEMM + GB_BUILD, 256, 0, stream>>>(
        x, Wb, b, mag_w, mag_b, attn_w, ei, deg, csr, hb, es);
    k_agg<<<N_NODES / 4, 256, 0, stream>>>(hb, deg, csr, es, out);
}